// Round 3
// baseline (377.704 us; speedup 1.0000x reference)
//
#include <hip/hip_runtime.h>
#include <hip/hip_bf16.h>

typedef __attribute__((ext_vector_type(8))) short bf16x8_t;
typedef __attribute__((ext_vector_type(4))) float f32x4_t;
typedef unsigned short u16;
typedef unsigned int u32;

__device__ __forceinline__ u16 f2bf(float f) {
  union { float f; u32 u; } v; v.f = f;
  u32 u = v.u;
  return (u16)((u + 0x7fffu + ((u >> 16) & 1u)) >> 16);
}

// ---------------- setup kernel A: kvp GEMM (blocks 0..351) + Wq cast (352..479)
__global__ void k_setupA(const float* __restrict__ kv, const float* __restrict__ Wkv,
                         const float* __restrict__ Wq,
                         float* __restrict__ kvp, u16* __restrict__ Wq_bf) {
  __shared__ float kvL[7 * 768];
  const int bx = blockIdx.x;
  const int tid = threadIdx.x;
  if (bx < 352) {
    const int jc = bx & 15, lt = (bx >> 4) % 11, b = bx / 176;
    const float* kvb = kv + ((size_t)b * 77 + (size_t)lt * 7) * 768;
    for (int i = tid; i < 7 * 768 / 4; i += 256)
      reinterpret_cast<float4*>(kvL)[i] = reinterpret_cast<const float4*>(kvb)[i];
    __syncthreads();
    const int j = jc * 64 + (tid & 63);
    const int lgc = tid >> 6;
    const bool has1 = (lgc < 3);
    float a0 = 0.f, a1 = 0.f;
    const float4* Wr = reinterpret_cast<const float4*>(Wkv + (size_t)j * 768);
    const float4* k0 = reinterpret_cast<const float4*>(kvL + lgc * 768);
    const float4* k1 = reinterpret_cast<const float4*>(kvL + (lgc + 4) * 768);
    #pragma unroll 4
    for (int k4 = 0; k4 < 192; ++k4) {
      float4 wv = Wr[k4];
      float4 x0 = k0[k4];
      a0 += wv.x * x0.x + wv.y * x0.y + wv.z * x0.z + wv.w * x0.w;
      if (has1) {
        float4 x1 = k1[k4];
        a1 += wv.x * x1.x + wv.y * x1.y + wv.z * x1.z + wv.w * x1.w;
      }
    }
    const int lbase = b * 77 + lt * 7;
    kvp[(size_t)(lbase + lgc) * 1024 + j] = a0;
    if (has1) kvp[(size_t)(lbase + lgc + 4) * 1024 + j] = a1;
  } else {
    int i = (bx - 352) * 256 + tid;
    float4 v = reinterpret_cast<const float4*>(Wq)[i];
    uint2 p;
    p.x = (u32)f2bf(v.x) | ((u32)f2bf(v.y) << 16);
    p.y = (u32)f2bf(v.z) | ((u32)f2bf(v.w) << 16);
    reinterpret_cast<uint2*>(Wq_bf)[i] = p;
  }
}

// ---------------- setup kernel B: k-softmax + context + M, fused. grid (8,2), 256 thr
__global__ void k_setupB(const float* __restrict__ kvp, const float* __restrict__ Wout,
                         u16* __restrict__ M_bf) {
  extern __shared__ float sm[];
  float* ks   = sm;           // 77*64 = 4928
  float* vs   = sm + 4928;    // 4928
  float* red  = sm + 9856;    // 256
  float* mcol = sm + 10112;   // 64
  float* icol = sm + 10176;   // 64
  float* ctxl = sm + 10240;   // [e][d] 4096
  float* Wt   = sm + 14336;   // [e][257] padded, 16448  -> total 30784 f = 123136 B
  const int h = blockIdx.x, b = blockIdx.y;
  const int tid = threadIdx.x;
  const float* base = kvp + (size_t)b * 77 * 1024;
  for (int i = tid; i < 77 * 64; i += 256) {
    int ll = i >> 6, d = i & 63;
    ks[i] = base[(size_t)ll * 1024 + h * 64 + d];
    vs[i] = base[(size_t)ll * 1024 + 512 + h * 64 + d];
  }
  for (int i = tid; i < 16384; i += 256) {
    int o = i >> 6, e = i & 63;
    Wt[e * 257 + o] = Wout[(size_t)o * 512 + h * 64 + e];
  }
  __syncthreads();
  const int d = tid & 63, part = tid >> 6;
  float m = -1e30f;
  for (int ll = part; ll < 77; ll += 4) m = fmaxf(m, ks[ll * 64 + d]);
  red[part * 64 + d] = m;
  __syncthreads();
  float mfull = fmaxf(fmaxf(red[d], red[64 + d]), fmaxf(red[128 + d], red[192 + d]));
  float s = 0.f;
  for (int ll = part; ll < 77; ll += 4) s += __expf(ks[ll * 64 + d] - mfull);
  __syncthreads();
  red[part * 64 + d] = s;
  __syncthreads();
  if (part == 0) {
    float S = red[d] + red[64 + d] + red[128 + d] + red[192 + d];
    mcol[d] = mfull;
    icol[d] = 1.0f / S;
  }
  __syncthreads();
  for (int i = tid; i < 77 * 64; i += 256) {
    int dd = i & 63;
    ks[i] = __expf(ks[i] - mcol[dd]) * icol[dd];
  }
  __syncthreads();
  // context: thread (dg, eg) computes ctx[d=dg*4..][e=eg*4..]
  const int dg = tid & 15, eg = tid >> 4;
  float acc[4][4];
  #pragma unroll
  for (int a = 0; a < 4; ++a)
    #pragma unroll
    for (int c = 0; c < 4; ++c) acc[a][c] = 0.f;
  for (int ll = 0; ll < 77; ++ll) {
    float4 kk = *reinterpret_cast<const float4*>(ks + ll * 64 + dg * 4);
    float4 vv = *reinterpret_cast<const float4*>(vs + ll * 64 + eg * 4);
    float kd[4] = {kk.x, kk.y, kk.z, kk.w};
    float ve[4] = {vv.x, vv.y, vv.z, vv.w};
    #pragma unroll
    for (int di = 0; di < 4; ++di)
      #pragma unroll
      for (int ei = 0; ei < 4; ++ei) acc[di][ei] += kd[di] * ve[ei];
  }
  // write ctxl[e][d]
  #pragma unroll
  for (int ei = 0; ei < 4; ++ei) {
    float4 row;
    row.x = acc[0][ei]; row.y = acc[1][ei]; row.z = acc[2][ei]; row.w = acc[3][ei];
    *reinterpret_cast<float4*>(ctxl + (size_t)(eg * 4 + ei) * 64 + dg * 4) = row;
  }
  __syncthreads();
  // M[o][d] = sum_e Wout[o][h*64+e] * ctx[d][e]
  // thread: og = tid&15 -> o = og*16 + oi (oi 0..15, covers 0..255)
  //         dgm = tid>>4 -> d = dgm*4 + di (covers 0..63)
  const int og = tid & 15, dgm = tid >> 4;
  float am[16][4];
  #pragma unroll
  for (int a = 0; a < 16; ++a)
    #pragma unroll
    for (int c = 0; c < 4; ++c) am[a][c] = 0.f;
  for (int e = 0; e < 64; ++e) {
    float4 cv = *reinterpret_cast<const float4*>(ctxl + e * 64 + dgm * 4);  // ctx[d][e]
    float cd[4] = {cv.x, cv.y, cv.z, cv.w};
    const float* wrow = Wt + e * 257 + og * 16;
    #pragma unroll
    for (int oi = 0; oi < 16; ++oi) {
      float wo = wrow[oi];
      #pragma unroll
      for (int di = 0; di < 4; ++di) am[oi][di] += wo * cd[di];
    }
  }
  #pragma unroll
  for (int oi = 0; oi < 16; ++oi) {
    int o = og * 16 + oi;
    uint2 p;
    p.x = (u32)f2bf(am[oi][0]) | ((u32)f2bf(am[oi][1]) << 16);
    p.y = (u32)f2bf(am[oi][2]) | ((u32)f2bf(am[oi][3]) << 16);
    *reinterpret_cast<uint2*>(M_bf + ((size_t)((b * 8 + h) * 256 + o)) * 64 + dgm * 4) = p;
  }
}

// ---------------- fused main kernel: persistent, 256 blocks x 4 tiles ----------------
__global__ __launch_bounds__(512, 2) void k_main(
    const float* __restrict__ x, const u16* __restrict__ Wq_bf,
    const u16* __restrict__ M_bf, const float* __restrict__ bout,
    float* __restrict__ out) {
  extern __shared__ char smem[];
  u16* Xl = reinterpret_cast<u16*>(smem);             // [128 n][256 c] bf16 swz, 64 KB
  u16* Wl = reinterpret_cast<u16*>(smem + 65536);     // [64 d][256 c] bf16 swz, 32 KB
  u16* Ml = reinterpret_cast<u16*>(smem + 98304);     // [256 o][64 d] bf16 swz, 32 KB
  u16* QT = reinterpret_cast<u16*>(smem + 131072);    // [128 n][64 d] bf16 swz, 16 KB
  float* sred = reinterpret_cast<float*>(smem + 147456);  // 4*128 f32, 2 KB

  const int tid = threadIdx.x;
  const int w = tid >> 6, l = tid & 63;
  const int lg = l >> 4, l15 = l & 15;
  const int wm1 = w >> 2, wn1 = w & 3;  // GEMM1: 2m x 4n
  const int wm2 = w >> 1, wn2 = w & 1;  // GEMM2: 4m x 2n
  const int sn = tid & 127;             // staging: pixel row
  const int cq = tid >> 7;              // staging: c-quarter

  const int T0 = blockIdx.x * 4;
  const int b = T0 >> 9;                // same batch for all 4 tiles
  const float* xb_base = x + (size_t)b * 256 * 65536;

  // ---- prologue: stage tile-0 X (fp32 [c][n] -> bf16 LDS [n][c] swizzled)
  {
    const float* xb = xb_base + (T0 & 511) * 128;
    #pragma unroll 4
    for (int it = 0; it < 16; ++it) {
      const int c0 = it * 16 + cq * 4;
      float f0 = xb[(size_t)(c0 + 0) * 65536 + sn];
      float f1 = xb[(size_t)(c0 + 1) * 65536 + sn];
      float f2 = xb[(size_t)(c0 + 2) * 65536 + sn];
      float f3 = xb[(size_t)(c0 + 3) * 65536 + sn];
      uint2 p;
      p.x = (u32)f2bf(f0) | ((u32)f2bf(f1) << 16);
      p.y = (u32)f2bf(f2) | ((u32)f2bf(f3) << 16);
      u32 boff = (u32)sn * 512u + (((u32)c0 * 2u) ^ (((u32)sn & 7u) << 4));
      *reinterpret_cast<uint2*>(reinterpret_cast<char*>(Xl) + boff) = p;
    }
  }
  // ---- prologue: stage Wl(0)
  {
    #pragma unroll
    for (int it = 0; it < 4; ++it) {
      int fidx = tid + it * 512;
      int row = fidx >> 5, seg = fidx & 31;
      uint4 v = *reinterpret_cast<const uint4*>(Wq_bf + (size_t)row * 256 + seg * 8);
      u32 boff = (u32)row * 512u + (((u32)seg * 16u) ^ (((u32)row & 7u) << 4));
      *reinterpret_cast<uint4*>(reinterpret_cast<char*>(Wl) + boff) = v;
    }
  }

  const f32x4_t fzero = {0.f, 0.f, 0.f, 0.f};
  f32x4_t acc2[4][4];
  #pragma unroll
  for (int i = 0; i < 4; ++i)
    #pragma unroll
    for (int j = 0; j < 4; ++j) acc2[i][j] = fzero;

  __syncthreads();

  for (int t = 0; t < 4; ++t) {
    const int n0 = ((T0 + t) & 511) * 128;

    // ---- extract X fragments to registers (head-invariant GEMM1 B operand)
    bf16x8_t xf[2][8];
    {
      const int cn0 = wn1 * 32 + l15, cn1 = cn0 + 16;
      #pragma unroll
      for (int ks = 0; ks < 8; ++ks) {
        u32 ko = (u32)(ks * 64 + lg * 16);
        xf[0][ks] = *reinterpret_cast<const bf16x8_t*>(reinterpret_cast<const char*>(Xl) +
                     (u32)cn0 * 512u + (ko ^ (((u32)cn0 & 7u) << 4)));
        xf[1][ks] = *reinterpret_cast<const bf16x8_t*>(reinterpret_cast<const char*>(Xl) +
                     (u32)cn1 * 512u + (ko ^ (((u32)cn1 & 7u) << 4)));
      }
    }
    __syncthreads();  // b0: extraction done -> Xl free for next-tile prefetch

    const bool pft = (t < 3);
    const float* xbn = xb_base + ((T0 + t + 1) & 511) * 128;

    for (int h = 0; h < 8; ++h) {
      // -- issue next-tile X prefetch chunk (HBM latency hides under GEMM1)
      float pf[8];
      if (pft) {
        #pragma unroll
        for (int j = 0; j < 2; ++j) {
          const int c0 = (2 * h + j) * 16 + cq * 4;
          #pragma unroll
          for (int kk = 0; kk < 4; ++kk)
            pf[j * 4 + kk] = xbn[(size_t)(c0 + kk) * 65536 + sn];
        }
      }
      // -- issue Ml(h) + Wl(h+1) staging loads into regs (L2/L3-hot)
      uint4 mlv[4], wlv[4];
      {
        const u16* msrc = M_bf + (size_t)(b * 8 + h) * 16384;
        #pragma unroll
        for (int it = 0; it < 4; ++it) {
          int fidx = tid + it * 512;
          mlv[it] = *reinterpret_cast<const uint4*>(msrc + (size_t)(fidx >> 3) * 64 + (fidx & 7) * 8);
        }
        const u16* wsrc = Wq_bf + (size_t)((h + 1) & 7) * 16384;
        #pragma unroll
        for (int it = 0; it < 4; ++it) {
          int fidx = tid + it * 512;
          wlv[it] = *reinterpret_cast<const uint4*>(wsrc + (size_t)(fidx >> 5) * 256 + (fidx & 31) * 8);
        }
      }

      // ---- GEMM1: Q[64 d][128 n] = Wq_h @ X   (B from registers)
      f32x4_t q[2][2];
      q[0][0] = fzero; q[0][1] = fzero; q[1][0] = fzero; q[1][1] = fzero;
      {
        const int r0 = wm1 * 32 + l15, r1 = r0 + 16;
        #pragma unroll
        for (int ks = 0; ks < 8; ++ks) {
          u32 ko = (u32)(ks * 64 + lg * 16);
          bf16x8_t a0 = *reinterpret_cast<const bf16x8_t*>(reinterpret_cast<const char*>(Wl) +
                         (u32)r0 * 512u + (ko ^ (((u32)r0 & 7u) << 4)));
          bf16x8_t a1 = *reinterpret_cast<const bf16x8_t*>(reinterpret_cast<const char*>(Wl) +
                         (u32)r1 * 512u + (ko ^ (((u32)r1 & 7u) << 4)));
          q[0][0] = __builtin_amdgcn_mfma_f32_16x16x32_bf16(a0, xf[0][ks], q[0][0], 0, 0, 0);
          q[0][1] = __builtin_amdgcn_mfma_f32_16x16x32_bf16(a0, xf[1][ks], q[0][1], 0, 0, 0);
          q[1][0] = __builtin_amdgcn_mfma_f32_16x16x32_bf16(a1, xf[0][ks], q[1][0], 0, 0, 0);
          q[1][1] = __builtin_amdgcn_mfma_f32_16x16x32_bf16(a1, xf[1][ks], q[1][1], 0, 0, 0);
        }
      }

      // ---- partial max, cross-wave combine setup
      float pm[2];
      #pragma unroll
      for (int nf = 0; nf < 2; ++nf) {
        float m = fmaxf(fmaxf(fmaxf(q[0][nf][0], q[0][nf][1]), fmaxf(q[0][nf][2], q[0][nf][3])),
                        fmaxf(fmaxf(q[1][nf][0], q[1][nf][1]), fmaxf(q[1][nf][2], q[1][nf][3])));
        m = fmaxf(m, __shfl_xor(m, 16, 64));
        m = fmaxf(m, __shfl_xor(m, 32, 64));
        pm[nf] = m;
      }
      const int col0 = wn1 * 32 + l15, col1 = col0 + 16;
      if (lg == 0) {
        sred[(wm1 * 2 + 0) * 128 + col0] = pm[0];
        sred[(wm1 * 2 + 0) * 128 + col1] = pm[1];
      }
      __syncthreads();  // b2: GEMM1 Wl-reads done; pm visible; Ml/QT(h-1) reads done

      // -- LDS writes for staged data (regs -> LDS)
      #pragma unroll
      for (int it = 0; it < 4; ++it) {
        int fidx = tid + it * 512;
        int row = fidx >> 3, seg = fidx & 7;
        u32 boff = (u32)row * 128u + (((u32)seg * 16u) ^ (((u32)row & 7u) << 4));
        *reinterpret_cast<uint4*>(reinterpret_cast<char*>(Ml) + boff) = mlv[it];
      }
      #pragma unroll
      for (int it = 0; it < 4; ++it) {
        int fidx = tid + it * 512;
        int row = fidx >> 5, seg = fidx & 31;
        u32 boff = (u32)row * 512u + (((u32)seg * 16u) ^ (((u32)row & 7u) << 4));
        *reinterpret_cast<uint4*>(reinterpret_cast<char*>(Wl) + boff) = wlv[it];
      }
      if (pft) {
        #pragma unroll
        for (int j = 0; j < 2; ++j) {
          const int c0 = (2 * h + j) * 16 + cq * 4;
          uint2 p;
          p.x = (u32)f2bf(pf[j * 4 + 0]) | ((u32)f2bf(pf[j * 4 + 1]) << 16);
          p.y = (u32)f2bf(pf[j * 4 + 2]) | ((u32)f2bf(pf[j * 4 + 3]) << 16);
          u32 boff = (u32)sn * 512u + (((u32)c0 * 2u) ^ (((u32)sn & 7u) << 4));
          *reinterpret_cast<uint2*>(reinterpret_cast<char*>(Xl) + boff) = p;
        }
      }

      // ---- softmax finish
      float mf0 = fmaxf(sred[0 * 128 + col0], sred[2 * 128 + col0]);
      float mf1 = fmaxf(sred[0 * 128 + col1], sred[2 * 128 + col1]);
      float ps[2] = {0.f, 0.f};
      #pragma unroll
      for (int mf = 0; mf < 2; ++mf)
        #pragma unroll
        for (int r = 0; r < 4; ++r) {
          q[mf][0][r] = __expf(q[mf][0][r] - mf0); ps[0] += q[mf][0][r];
          q[mf][1][r] = __expf(q[mf][1][r] - mf1); ps[1] += q[mf][1][r];
        }
      #pragma unroll
      for (int nf = 0; nf < 2; ++nf) {
        ps[nf] += __shfl_xor(ps[nf], 16, 64);
        ps[nf] += __shfl_xor(ps[nf], 32, 64);
      }
      if (lg == 0) {
        sred[(wm1 * 2 + 1) * 128 + col0] = ps[0];
        sred[(wm1 * 2 + 1) * 128 + col1] = ps[1];
      }
      __syncthreads();  // b3: ps visible; staged Wl/Ml visible

      float sc[2];
      sc[0] = 0.125f / (sred[1 * 128 + col0] + sred[3 * 128 + col0]);
      sc[1] = 0.125f / (sred[1 * 128 + col1] + sred[3 * 128 + col1]);

      // ---- write Qsm to QT [n][d] bf16 swizzled
      #pragma unroll
      for (int mf = 0; mf < 2; ++mf)
        #pragma unroll
        for (int nf = 0; nf < 2; ++nf) {
          int col = wn1 * 32 + nf * 16 + l15;
          int row0 = wm1 * 32 + mf * 16 + lg * 4;
          uint2 p;
          p.x = (u32)f2bf(q[mf][nf][0] * sc[nf]) | ((u32)f2bf(q[mf][nf][1] * sc[nf]) << 16);
          p.y = (u32)f2bf(q[mf][nf][2] * sc[nf]) | ((u32)f2bf(q[mf][nf][3] * sc[nf]) << 16);
          u32 boff = (u32)col * 128u + (((u32)row0 * 2u) ^ (((u32)col & 7u) << 4));
          *reinterpret_cast<uint2*>(reinterpret_cast<char*>(QT) + boff) = p;
        }
      __syncthreads();  // b4: QT ready

      // ---- GEMM2: Out[256 o][128 n] += M_h @ Qsm
      #pragma unroll
      for (int kb = 0; kb < 2; ++kb) {
        const u32 ko = (u32)(kb * 64 + lg * 16);
        bf16x8_t a[4], bq[4];
        #pragma unroll
        for (int mf = 0; mf < 4; ++mf) {
          int row = wm2 * 64 + mf * 16 + l15;
          a[mf] = *reinterpret_cast<const bf16x8_t*>(reinterpret_cast<const char*>(Ml) +
                   (u32)row * 128u + (ko ^ (((u32)row & 7u) << 4)));
        }
        #pragma unroll
        for (int nf = 0; nf < 4; ++nf) {
          int col = wn2 * 64 + nf * 16 + l15;
          bq[nf] = *reinterpret_cast<const bf16x8_t*>(reinterpret_cast<const char*>(QT) +
                    (u32)col * 128u + (ko ^ (((u32)col & 7u) << 4)));
        }
        #pragma unroll
        for (int mf = 0; mf < 4; ++mf)
          #pragma unroll
          for (int nf = 0; nf < 4; ++nf)
            acc2[mf][nf] = __builtin_amdgcn_mfma_f32_16x16x32_bf16(a[mf], bq[nf], acc2[mf][nf], 0, 0, 0);
      }
    }

    // ---- epilogue: bias + store (fire-and-forget; overlaps next tile), reset acc
    #pragma unroll
    for (int mf = 0; mf < 4; ++mf) {
      #pragma unroll
      for (int r = 0; r < 4; ++r) {
        int o = wm2 * 64 + mf * 16 + lg * 4 + r;
        float bo = bout[o];
        #pragma unroll
        for (int nf = 0; nf < 4; ++nf) {
          int nn = n0 + wn2 * 64 + nf * 16 + l15;
          out[((size_t)b * 256 + o) * 65536 + nn] = acc2[mf][nf][r] + bo;
        }
      }
    }
    #pragma unroll
    for (int i = 0; i < 4; ++i)
      #pragma unroll
      for (int j = 0; j < 4; ++j) acc2[i][j] = fzero;
    __syncthreads();  // tile end: prefetch writes complete; QT/Ml reads done
  }
}

extern "C" void kernel_launch(void* const* d_in, const int* in_sizes, int n_in,
                              void* d_out, int out_size, void* d_ws, size_t ws_size,
                              hipStream_t stream) {
  (void)in_sizes; (void)n_in; (void)out_size; (void)ws_size;
  const float* x    = (const float*)d_in[0];
  const float* kv   = (const float*)d_in[1];
  const float* Wq   = (const float*)d_in[2];
  const float* Wkv  = (const float*)d_in[3];
  const float* Wout = (const float*)d_in[4];
  const float* bout = (const float*)d_in[5];
  float* out = (float*)d_out;

  char* ws = (char*)d_ws;
  float* kvp   = (float*)(ws);                       // 2*77*1024*4   = 630784 B
  u16*   M_bf  = (u16*)(ws + 630784);                // 2*8*256*64*2  = 524288 B
  u16*   Wq_bf = (u16*)(ws + 630784 + 524288);       // 512*256*2     = 262144 B

  hipFuncSetAttribute(reinterpret_cast<const void*>(k_setupB),
                      hipFuncAttributeMaxDynamicSharedMemorySize, 123136);
  hipFuncSetAttribute(reinterpret_cast<const void*>(k_main),
                      hipFuncAttributeMaxDynamicSharedMemorySize, 149504);

  k_setupA<<<480, 256, 0, stream>>>(kv, Wkv, Wq, kvp, Wq_bf);
  k_setupB<<<dim3(8, 2), 256, 123136, stream>>>(kvp, Wout, M_bf);
  k_main<<<256, 512, 149504, stream>>>(x, Wq_bf, M_bf, bout, out);
}

// Round 5
// 260.593 us; speedup vs baseline: 1.4494x; 1.4494x over previous
//
#include <hip/hip_runtime.h>
#include <hip/hip_bf16.h>

typedef __attribute__((ext_vector_type(8))) short bf16x8_t;
typedef __attribute__((ext_vector_type(4))) float f32x4_t;
typedef unsigned short u16;
typedef unsigned int u32;

__device__ __forceinline__ u16 f2bf(float f) {
  union { float f; u32 u; } v; v.f = f;
  u32 u = v.u;
  return (u16)((u + 0x7fffu + ((u >> 16) & 1u)) >> 16);
}

// ---------------- setup kernel A: kvp GEMM (blocks 0..351) + Wq cast (352..479)
__global__ void k_setupA(const float* __restrict__ kv, const float* __restrict__ Wkv,
                         const float* __restrict__ Wq,
                         float* __restrict__ kvp, u16* __restrict__ Wq_bf) {
  __shared__ float kvL[7 * 768];
  const int bx = blockIdx.x;
  const int tid = threadIdx.x;
  if (bx < 352) {
    const int jc = bx & 15, lt = (bx >> 4) % 11, b = bx / 176;
    const float* kvb = kv + ((size_t)b * 77 + (size_t)lt * 7) * 768;
    for (int i = tid; i < 7 * 768 / 4; i += 256)
      reinterpret_cast<float4*>(kvL)[i] = reinterpret_cast<const float4*>(kvb)[i];
    __syncthreads();
    const int j = jc * 64 + (tid & 63);
    const int lgc = tid >> 6;
    const bool has1 = (lgc < 3);
    float a0 = 0.f, a1 = 0.f;
    const float4* Wr = reinterpret_cast<const float4*>(Wkv + (size_t)j * 768);
    const float4* k0 = reinterpret_cast<const float4*>(kvL + lgc * 768);
    const float4* k1 = reinterpret_cast<const float4*>(kvL + (lgc + 4) * 768);
    #pragma unroll 4
    for (int k4 = 0; k4 < 192; ++k4) {
      float4 wv = Wr[k4];
      float4 x0 = k0[k4];
      a0 += wv.x * x0.x + wv.y * x0.y + wv.z * x0.z + wv.w * x0.w;
      if (has1) {
        float4 x1 = k1[k4];
        a1 += wv.x * x1.x + wv.y * x1.y + wv.z * x1.z + wv.w * x1.w;
      }
    }
    const int lbase = b * 77 + lt * 7;
    kvp[(size_t)(lbase + lgc) * 1024 + j] = a0;
    if (has1) kvp[(size_t)(lbase + lgc + 4) * 1024 + j] = a1;
  } else {
    int i = (bx - 352) * 256 + tid;
    float4 v = reinterpret_cast<const float4*>(Wq)[i];
    uint2 p;
    p.x = (u32)f2bf(v.x) | ((u32)f2bf(v.y) << 16);
    p.y = (u32)f2bf(v.z) | ((u32)f2bf(v.w) << 16);
    reinterpret_cast<uint2*>(Wq_bf)[i] = p;
  }
}

// ---------------- setup kernel B: k-softmax + context + M, fused. grid (8,2), 256 thr
__global__ void k_setupB(const float* __restrict__ kvp, const float* __restrict__ Wout,
                         u16* __restrict__ M_bf) {
  extern __shared__ float sm[];
  float* ks   = sm;           // 77*64 = 4928
  float* vs   = sm + 4928;    // 4928
  float* red  = sm + 9856;    // 256
  float* mcol = sm + 10112;   // 64
  float* icol = sm + 10176;   // 64
  float* ctxl = sm + 10240;   // [e][d] 4096
  float* Wt   = sm + 14336;   // [e][257] padded, 16448  -> total 30784 f = 123136 B
  const int h = blockIdx.x, b = blockIdx.y;
  const int tid = threadIdx.x;
  const float* base = kvp + (size_t)b * 77 * 1024;
  for (int i = tid; i < 77 * 64; i += 256) {
    int ll = i >> 6, d = i & 63;
    ks[i] = base[(size_t)ll * 1024 + h * 64 + d];
    vs[i] = base[(size_t)ll * 1024 + 512 + h * 64 + d];
  }
  for (int i = tid; i < 16384; i += 256) {
    int o = i >> 6, e = i & 63;
    Wt[e * 257 + o] = Wout[(size_t)o * 512 + h * 64 + e];
  }
  __syncthreads();
  const int d = tid & 63, part = tid >> 6;
  float m = -1e30f;
  for (int ll = part; ll < 77; ll += 4) m = fmaxf(m, ks[ll * 64 + d]);
  red[part * 64 + d] = m;
  __syncthreads();
  float mfull = fmaxf(fmaxf(red[d], red[64 + d]), fmaxf(red[128 + d], red[192 + d]));
  float s = 0.f;
  for (int ll = part; ll < 77; ll += 4) s += __expf(ks[ll * 64 + d] - mfull);
  __syncthreads();
  red[part * 64 + d] = s;
  __syncthreads();
  if (part == 0) {
    float S = red[d] + red[64 + d] + red[128 + d] + red[192 + d];
    mcol[d] = mfull;
    icol[d] = 1.0f / S;
  }
  __syncthreads();
  for (int i = tid; i < 77 * 64; i += 256) {
    int dd = i & 63;
    ks[i] = __expf(ks[i] - mcol[dd]) * icol[dd];
  }
  __syncthreads();
  const int dg = tid & 15, eg = tid >> 4;
  float acc[4][4];
  #pragma unroll
  for (int a = 0; a < 4; ++a)
    #pragma unroll
    for (int c = 0; c < 4; ++c) acc[a][c] = 0.f;
  for (int ll = 0; ll < 77; ++ll) {
    float4 kk = *reinterpret_cast<const float4*>(ks + ll * 64 + dg * 4);
    float4 vv = *reinterpret_cast<const float4*>(vs + ll * 64 + eg * 4);
    float kd[4] = {kk.x, kk.y, kk.z, kk.w};
    float ve[4] = {vv.x, vv.y, vv.z, vv.w};
    #pragma unroll
    for (int di = 0; di < 4; ++di)
      #pragma unroll
      for (int ei = 0; ei < 4; ++ei) acc[di][ei] += kd[di] * ve[ei];
  }
  #pragma unroll
  for (int ei = 0; ei < 4; ++ei) {
    float4 row;
    row.x = acc[0][ei]; row.y = acc[1][ei]; row.z = acc[2][ei]; row.w = acc[3][ei];
    *reinterpret_cast<float4*>(ctxl + (size_t)(eg * 4 + ei) * 64 + dg * 4) = row;
  }
  __syncthreads();
  // M[o][d]: og = tid&15 -> o = og*16+oi; dgm = tid>>4 -> d = dgm*4+di
  const int og = tid & 15, dgm = tid >> 4;
  float am[16][4];
  #pragma unroll
  for (int a = 0; a < 16; ++a)
    #pragma unroll
    for (int c = 0; c < 4; ++c) am[a][c] = 0.f;
  for (int e = 0; e < 64; ++e) {
    float4 cv = *reinterpret_cast<const float4*>(ctxl + e * 64 + dgm * 4);
    float cd[4] = {cv.x, cv.y, cv.z, cv.w};
    const float* wrow = Wt + e * 257 + og * 16;
    #pragma unroll
    for (int oi = 0; oi < 16; ++oi) {
      float wo = wrow[oi];
      #pragma unroll
      for (int di = 0; di < 4; ++di) am[oi][di] += wo * cd[di];
    }
  }
  #pragma unroll
  for (int oi = 0; oi < 16; ++oi) {
    int o = og * 16 + oi;
    uint2 p;
    p.x = (u32)f2bf(am[oi][0]) | ((u32)f2bf(am[oi][1]) << 16);
    p.y = (u32)f2bf(am[oi][2]) | ((u32)f2bf(am[oi][3]) << 16);
    *reinterpret_cast<uint2*>(M_bf + ((size_t)((b * 8 + h) * 256 + o)) * 64 + dgm * 4) = p;
  }
}

// ---------------- fused main kernel: BN=64, 4 waves, 3 blocks/CU, direct-global A
// grid 2048: block = one 64-pixel tile of one batch (1024 tiles/batch).
__global__ __launch_bounds__(256, 3) void k_main(
    const float* __restrict__ x, const u16* __restrict__ Wq_bf,
    const u16* __restrict__ M_bf, const float* __restrict__ bout,
    float* __restrict__ out) {
  __shared__ u16 Xl[64 * 256];        // [n][c] bf16 swizzled, 32 KB
  __shared__ u16 QT[64 * 64];         // [n][d] bf16 swizzled, 8 KB
  __shared__ float sred[2][4][64];    // [kind][wave][col], 2 KB

  const int tid = threadIdx.x;
  const int w = tid >> 6, l = tid & 63;
  const int lg = l >> 4, l15 = l & 15;

  const int bi = blockIdx.x;
  const int b = bi >> 10;             // 1024 tiles per batch
  const int n0 = (bi & 1023) * 64;
  const float* xb = x + (size_t)b * 16777216 + n0;

  // ---- stage X tile: fp32 [c][n] -> bf16 LDS [n][c] swizzled
  {
    const int n = l;       // wave w handles c-quarter w
    #pragma unroll
    for (int it = 0; it < 16; ++it) {
      const int c0 = it * 16 + w * 4;
      float f0 = xb[(size_t)(c0 + 0) * 65536 + n];
      float f1 = xb[(size_t)(c0 + 1) * 65536 + n];
      float f2 = xb[(size_t)(c0 + 2) * 65536 + n];
      float f3 = xb[(size_t)(c0 + 3) * 65536 + n];
      uint2 p;
      p.x = (u32)f2bf(f0) | ((u32)f2bf(f1) << 16);
      p.y = (u32)f2bf(f2) | ((u32)f2bf(f3) << 16);
      u32 boff = (u32)n * 512u + (((u32)(c0 * 2)) ^ (((u32)n & 7u) << 4));
      *reinterpret_cast<uint2*>(reinterpret_cast<char*>(Xl) + boff) = p;
    }
  }

  const f32x4_t fzero = {0.f, 0.f, 0.f, 0.f};
  f32x4_t acc2[4][4];   // [mf][nf]: rows w*64+mf*16+lg*4+r, cols nf*16+l15
  #pragma unroll
  for (int i = 0; i < 4; ++i)
    #pragma unroll
    for (int j = 0; j < 4; ++j) acc2[i][j] = fzero;

  __syncthreads();

  for (int h = 0; h < 8; ++h) {
    // ---- GEMM1: Q[64 d][64 n] = Wq_h @ X.  A direct from global (L2-hot),
    // wave w owns d-rows w*16..w*16+15 (no inter-wave dup). B from Xl.
    f32x4_t q[4];
    q[0] = fzero; q[1] = fzero; q[2] = fzero; q[3] = fzero;
    {
      const u16* wsrc = Wq_bf + (size_t)h * 16384 + (size_t)(w * 16 + l15) * 256;
      #pragma unroll
      for (int ks = 0; ks < 8; ++ks) {
        bf16x8_t a = *reinterpret_cast<const bf16x8_t*>(wsrc + ks * 32 + lg * 8);
        #pragma unroll
        for (int nf = 0; nf < 4; ++nf) {
          const int cn = nf * 16 + l15;
          bf16x8_t bx = *reinterpret_cast<const bf16x8_t*>(reinterpret_cast<const char*>(Xl) +
                         (u32)cn * 512u + (((u32)(ks * 64 + lg * 16)) ^ (((u32)cn & 7u) << 4)));
          q[nf] = __builtin_amdgcn_mfma_f32_16x16x32_bf16(a, bx, q[nf], 0, 0, 0);
        }
      }
    }

    // ---- softmax over d (64 rows) per column; wave partial = 16 rows
    float pm[4];
    #pragma unroll
    for (int nf = 0; nf < 4; ++nf) {
      float m = fmaxf(fmaxf(q[nf][0], q[nf][1]), fmaxf(q[nf][2], q[nf][3]));
      m = fmaxf(m, __shfl_xor(m, 16, 64));
      m = fmaxf(m, __shfl_xor(m, 32, 64));
      pm[nf] = m;
    }
    if (lg == 0) {
      #pragma unroll
      for (int nf = 0; nf < 4; ++nf) sred[0][w][nf * 16 + l15] = pm[nf];
    }
    __syncthreads();  // b1

    float ps[4];
    #pragma unroll
    for (int nf = 0; nf < 4; ++nf) {
      const int col = nf * 16 + l15;
      float mf = fmaxf(fmaxf(sred[0][0][col], sred[0][1][col]),
                       fmaxf(sred[0][2][col], sred[0][3][col]));
      float s = 0.f;
      #pragma unroll
      for (int r = 0; r < 4; ++r) { q[nf][r] = __expf(q[nf][r] - mf); s += q[nf][r]; }
      s += __shfl_xor(s, 16, 64);
      s += __shfl_xor(s, 32, 64);
      ps[nf] = s;
    }
    if (lg == 0) {
      #pragma unroll
      for (int nf = 0; nf < 4; ++nf) sred[1][w][nf * 16 + l15] = ps[nf];
    }
    __syncthreads();  // b2

    #pragma unroll
    for (int nf = 0; nf < 4; ++nf) {
      const int col = nf * 16 + l15;
      float S = (sred[1][0][col] + sred[1][1][col]) + (sred[1][2][col] + sred[1][3][col]);
      float sc = 0.125f / S;
      const int row0 = w * 16 + lg * 4;
      uint2 p;
      p.x = (u32)f2bf(q[nf][0] * sc) | ((u32)f2bf(q[nf][1] * sc) << 16);
      p.y = (u32)f2bf(q[nf][2] * sc) | ((u32)f2bf(q[nf][3] * sc) << 16);
      u32 boff = (u32)col * 128u + (((u32)(row0 * 2)) ^ (((u32)col & 7u) << 4));
      *reinterpret_cast<uint2*>(reinterpret_cast<char*>(QT) + boff) = p;
    }
    __syncthreads();  // b3: QT ready

    // ---- GEMM2: Out[256 o][64 n] += M_h @ Qsm.  A direct from global (L2-hot),
    // wave w owns o-rows w*64..w*64+63.
    {
      const u16* msrc = M_bf + ((size_t)(b * 8 + h) * 256 + w * 64 + l15) * 64;
      #pragma unroll
      for (int kb = 0; kb < 2; ++kb) {
        bf16x8_t a[4], bq[4];
        #pragma unroll
        for (int mf = 0; mf < 4; ++mf)
          a[mf] = *reinterpret_cast<const bf16x8_t*>(msrc + (size_t)mf * 1024 + kb * 32 + lg * 8);
        #pragma unroll
        for (int nf = 0; nf < 4; ++nf) {
          const int col = nf * 16 + l15;
          bq[nf] = *reinterpret_cast<const bf16x8_t*>(reinterpret_cast<const char*>(QT) +
                    (u32)col * 128u + (((u32)(kb * 64 + lg * 16)) ^ (((u32)col & 7u) << 4)));
        }
        #pragma unroll
        for (int mf = 0; mf < 4; ++mf)
          #pragma unroll
          for (int nf = 0; nf < 4; ++nf)
            acc2[mf][nf] = __builtin_amdgcn_mfma_f32_16x16x32_bf16(a[mf], bq[nf], acc2[mf][nf], 0, 0, 0);
      }
    }
    // next head's sred/QT writes are separated from this head's reads by b1/b2/b3
  }

  // ---- epilogue: bias + store fp32
  #pragma unroll
  for (int mf = 0; mf < 4; ++mf) {
    #pragma unroll
    for (int r = 0; r < 4; ++r) {
      const int o = w * 64 + mf * 16 + lg * 4 + r;
      const float bo = bout[o];
      float* orow = out + ((size_t)b * 256 + o) * 65536 + n0;
      #pragma unroll
      for (int nf = 0; nf < 4; ++nf)
        orow[nf * 16 + l15] = acc2[mf][nf][r] + bo;
    }
  }
}

extern "C" void kernel_launch(void* const* d_in, const int* in_sizes, int n_in,
                              void* d_out, int out_size, void* d_ws, size_t ws_size,
                              hipStream_t stream) {
  (void)in_sizes; (void)n_in; (void)out_size; (void)ws_size;
  const float* x    = (const float*)d_in[0];
  const float* kv   = (const float*)d_in[1];
  const float* Wq   = (const float*)d_in[2];
  const float* Wkv  = (const float*)d_in[3];
  const float* Wout = (const float*)d_in[4];
  const float* bout = (const float*)d_in[5];
  float* out = (float*)d_out;

  char* ws = (char*)d_ws;
  float* kvp   = (float*)(ws);                       // 2*77*1024*4   = 630784 B
  u16*   M_bf  = (u16*)(ws + 630784);                // 2*8*256*64*2  = 524288 B
  u16*   Wq_bf = (u16*)(ws + 630784 + 524288);       // 512*256*2     = 262144 B

  hipFuncSetAttribute(reinterpret_cast<const void*>(k_setupB),
                      hipFuncAttributeMaxDynamicSharedMemorySize, 123136);

  k_setupA<<<480, 256, 0, stream>>>(kv, Wkv, Wq, kvp, Wq_bf);
  k_setupB<<<dim3(8, 2), 256, 123136, stream>>>(kvp, Wout, M_bf);
  k_main<<<2048, 256, 0, stream>>>(x, Wq_bf, M_bf, bout, out);
}